// Round 1
// baseline (338.557 us; speedup 1.0000x reference)
//
#include <hip/hip_runtime.h>
#include <hip/hip_bf16.h>

#define KK 9
#define PADK 4
#define CIN 64
#define COUT 64
#define LSEQ 131072
#define NB 4
#define TILE 64
#define XROWS 72          // TILE + KK - 1
#define XRS 72            // xt row stride (bf16 elems); 144 B rows, 16B aligned
#define NTILES 2048       // LSEQ / TILE
#define NPART 64

typedef __attribute__((ext_vector_type(8))) short v8s;
typedef __attribute__((ext_vector_type(4))) float v4f;

__device__ __forceinline__ unsigned short f2bf(float f) {
  __hip_bfloat16 h = __float2bfloat16(f);
  return *reinterpret_cast<unsigned short*>(&h);
}
__device__ __forceinline__ float bf2f(unsigned short s) {
  return __uint_as_float(((unsigned)s) << 16);
}

__device__ __forceinline__ void store_o(float* p, float v) { *p = v; }
__device__ __forceinline__ void store_o(__hip_bfloat16* p, float v) { *p = __float2bfloat16(v); }

// ---------------------------------------------------------------------------
// Repack W[Cout][Cin][K] fp32 -> bf16 A-fragments for mfma_f32_16x16x32_bf16,
// pre-swizzled: frag (k, s, mblk) is 1024 contiguous bytes, lane-major.
// A-layout: lane holds A[m = lane&15][kdim = (lane>>4)*8 + j], j=0..7.
// Here m -> o within mblk, kdim -> c = 32*s + q*8 + j.
// ---------------------------------------------------------------------------
__global__ void wtrans_kernel(const float* __restrict__ W, v8s* __restrict__ Wt) {
  int t = blockIdx.x * 256 + threadIdx.x;
  if (t >= KK * 2 * 4 * 64) return;
  int lane = t & 63;
  int frag = t >> 6;
  int mblk = frag & 3;
  int s    = (frag >> 2) & 1;
  int k    = frag >> 3;
  int m = lane & 15, q = lane >> 4;
  int o = mblk * 16 + m;
  union { v8s v; unsigned short h[8]; } u;
#pragma unroll
  for (int j = 0; j < 8; ++j) {
    int c = 32 * s + q * 8 + j;
    u.h[j] = f2bf(W[(o * CIN + c) * KK + k]);
  }
  Wt[t] = u.v;
}

// ---------------------------------------------------------------------------
// Weighted conv via MFMA. One wave = one (b, 64-wide l-tile), computing the
// full 64(o) x 64(l) output block with 4x4 16x16 accumulator fragments.
// Contraction dim = (c,k) = 576, looped k outer (9), c in 2 steps of 32.
// B-operand u[(c,k)][n] = x[c][n+k-4] * w[k][n] built in registers from LDS.
// ---------------------------------------------------------------------------
template <typename OutT>
__global__ __launch_bounds__(256, 2)
void conv_kernel(const float* __restrict__ x, const float* __restrict__ coords,
                 const v8s* __restrict__ Wt, OutT* __restrict__ cv,
                 float* __restrict__ stat_sum, float* __restrict__ stat_sq) {
  __shared__ __align__(16) __hip_bfloat16 xt[4][XROWS][XRS]; // x tile, [n'][c], bf16
  __shared__ float wt[4][KK][TILE];                          // gaussian weights
  __shared__ float ct[4][3][XROWS];                          // coords tile (zero-padded)

  const int wv   = threadIdx.x >> 6;
  const int lane = threadIdx.x & 63;
  const int gw   = blockIdx.x * 4 + wv;       // global wave-tile id, 0..8191
  const int b    = gw >> 11;                  // / NTILES
  const int tile = gw & (NTILES - 1);
  const int l0   = tile * TILE;
  const float* xb = x + (b * CIN) * LSEQ;
  const float* cb = coords + (b * 3) * LSEQ;
  const int m = lane & 15;
  const int q = lane >> 4;

  // ---- stage main x region (rows 4..67), transposed, bf16, c-pairs packed ----
  {
#pragma unroll
    for (int rep = 0; rep < 8; ++rep) {
      int p = q + 4 * rep;                    // c-pair index 0..31
      int c = 2 * p;
      const float* s0 = xb + c * LSEQ + l0 + 4 * m;   // m = chunk (lane&15)
      float4 a0 = *(const float4*)(s0);
      float4 a1 = *(const float4*)(s0 + LSEQ);
      float e0[4] = {a0.x, a0.y, a0.z, a0.w};
      float e1[4] = {a1.x, a1.y, a1.z, a1.w};
#pragma unroll
      for (int j = 0; j < 4; ++j) {
        unsigned pk = ((unsigned)f2bf(e1[j]) << 16) | (unsigned)f2bf(e0[j]);
        *(unsigned*)&xt[wv][4 + 4 * m + j][c] = pk;
      }
    }
  }
  // ---- halos (rows 0..3 and 68..71), zero-padded at sequence ends ----
  {
    int c = lane;
    float el[4] = {0.f, 0.f, 0.f, 0.f};
    float er[4] = {0.f, 0.f, 0.f, 0.f};
    if (tile != 0) {
#pragma unroll
      for (int j = 0; j < 4; ++j) el[j] = xb[c * LSEQ + l0 - 4 + j];
    }
    if (tile != NTILES - 1) {
#pragma unroll
      for (int j = 0; j < 4; ++j) er[j] = xb[c * LSEQ + l0 + TILE + j];
    }
#pragma unroll
    for (int j = 0; j < 4; ++j) {
      xt[wv][j][c]      = __float2bfloat16(el[j]);
      xt[wv][68 + j][c] = __float2bfloat16(er[j]);
    }
  }
  // ---- coords tile (zero-padded like jnp.pad) ----
  {
#pragma unroll
    for (int d = 0; d < 3; ++d) {
      for (int r = lane; r < XROWS; r += 64) {
        int l = l0 - PADK + r;
        float v = 0.f;
        if (l >= 0 && l < LSEQ) v = cb[d * LSEQ + l];
        ct[wv][d][r] = v;
      }
    }
  }
  __syncthreads();

  // ---- gaussian weights: w[k][n] = exp(-0.5 * |cpad[n+k-4] - c[n]|^2) ----
  {
    float cx = ct[wv][0][lane + PADK];
    float cy = ct[wv][1][lane + PADK];
    float cz = ct[wv][2][lane + PADK];
#pragma unroll
    for (int k = 0; k < KK; ++k) {
      float dx = ct[wv][0][lane + k] - cx;
      float dy = ct[wv][1][lane + k] - cy;
      float dz = ct[wv][2][lane + k] - cz;
      wt[wv][k][lane] = __expf(-0.5f * (dx * dx + dy * dy + dz * dz));
    }
  }
  __syncthreads();

  // ---- MFMA main loop ----
  v4f acc[4][4];
#pragma unroll
  for (int i = 0; i < 4; ++i)
#pragma unroll
    for (int j = 0; j < 4; ++j)
      acc[i][j] = (v4f){0.f, 0.f, 0.f, 0.f};

#pragma unroll 1
  for (int k = 0; k < KK; ++k) {
    v8s afr[2][4];
#pragma unroll
    for (int s = 0; s < 2; ++s)
#pragma unroll
      for (int mb = 0; mb < 4; ++mb)
        afr[s][mb] = Wt[((k * 2 + s) * 4 + mb) * 64 + lane];
#pragma unroll
    for (int nb = 0; nb < 4; ++nb) {
      float wsc = wt[wv][k][nb * 16 + m];
      const __hip_bfloat16* rowp = &xt[wv][nb * 16 + m + k][0];
#pragma unroll
      for (int s = 0; s < 2; ++s) {
        union { v8s v; unsigned u[4]; } bi, bo;
        bi.v = *(const v8s*)(rowp + q * 8 + 32 * s);
#pragma unroll
        for (int i = 0; i < 4; ++i) {
          float lo = __uint_as_float(bi.u[i] << 16) * wsc;
          float hi = __uint_as_float(bi.u[i] & 0xffff0000u) * wsc;
          bo.u[i] = ((unsigned)f2bf(hi) << 16) | (unsigned)f2bf(lo);
        }
#pragma unroll
        for (int mb = 0; mb < 4; ++mb)
          acc[mb][nb] = __builtin_amdgcn_mfma_f32_16x16x32_bf16(
              afr[s][mb], bo.v, acc[mb][nb], 0, 0, 0);
      }
    }
  }

  // ---- epilogue: store conv result + per-channel sum/sumsq partials ----
  const int part = gw & (NPART - 1);
  OutT* outb = cv + (b * COUT) * LSEQ;
#pragma unroll
  for (int mb = 0; mb < 4; ++mb) {
#pragma unroll
    for (int r = 0; r < 4; ++r) {
      int o = mb * 16 + q * 4 + r;   // C-layout: row = q*4 + reg
      float s1 = 0.f, s2 = 0.f;
#pragma unroll
      for (int nb = 0; nb < 4; ++nb) {
        float v = acc[mb][nb][r];
        s1 += v;
        s2 += v * v;
        store_o(&outb[o * LSEQ + l0 + nb * 16 + m], v);  // col = lane&15
      }
#pragma unroll
      for (int off = 1; off < 16; off <<= 1) {
        s1 += __shfl_xor(s1, off, 64);
        s2 += __shfl_xor(s2, off, 64);
      }
      if (m == 0) {
        atomicAdd(&stat_sum[part * COUT + o], s1);
        atomicAdd(&stat_sq [part * COUT + o], s2);
      }
    }
  }
}

// ---------------------------------------------------------------------------
// BN finalize: scale = gamma*rsqrt(var+eps), shift = beta - mean*scale.
// (Conv bias cancels exactly under training-mode BN, so it is skipped.)
// ---------------------------------------------------------------------------
__global__ void finalize_kernel(const float* __restrict__ stat_sum,
                                const float* __restrict__ stat_sq,
                                const float* __restrict__ gamma,
                                const float* __restrict__ beta,
                                float* __restrict__ ss) {
  int o = threadIdx.x;
  float s1 = 0.f, s2 = 0.f;
  for (int p = 0; p < NPART; ++p) {
    s1 += stat_sum[p * COUT + o];
    s2 += stat_sq [p * COUT + o];
  }
  const float invN = 1.0f / (float)(NB * LSEQ);
  float mean = s1 * invN;
  float var  = s2 * invN - mean * mean;   // biased, matches jnp.var
  float sc = gamma[o] * rsqrtf(var + 1e-5f);
  ss[o]        = sc;
  ss[COUT + o] = beta[o] - mean * sc;
}

// ---- BN apply + ReLU; one block = 2048 contiguous elems in one channel ----
__global__ __launch_bounds__(256)
void scale_f32_kernel(float* __restrict__ data, const float* __restrict__ ss) {
  const int blk = blockIdx.x;
  const int ch = (blk >> 6) & 63;   // L/2048 = 64 blocks per channel
  const float sc = ss[ch];
  const float sh = ss[COUT + ch];
  const int base = blk * 2048 + threadIdx.x * 8;
  float4 a = *(float4*)(data + base);
  float4 b = *(float4*)(data + base + 4);
  a.x = fmaxf(fmaf(a.x, sc, sh), 0.f);
  a.y = fmaxf(fmaf(a.y, sc, sh), 0.f);
  a.z = fmaxf(fmaf(a.z, sc, sh), 0.f);
  a.w = fmaxf(fmaf(a.w, sc, sh), 0.f);
  b.x = fmaxf(fmaf(b.x, sc, sh), 0.f);
  b.y = fmaxf(fmaf(b.y, sc, sh), 0.f);
  b.z = fmaxf(fmaf(b.z, sc, sh), 0.f);
  b.w = fmaxf(fmaf(b.w, sc, sh), 0.f);
  *(float4*)(data + base)     = a;
  *(float4*)(data + base + 4) = b;
}

__global__ __launch_bounds__(256)
void scale_bf16_kernel(const __hip_bfloat16* __restrict__ cvin,
                       const float* __restrict__ ss, float* __restrict__ out) {
  const int blk = blockIdx.x;
  const int ch = (blk >> 6) & 63;
  const float sc = ss[ch];
  const float sh = ss[COUT + ch];
  const int base = blk * 2048 + threadIdx.x * 8;
  union { v8s v; unsigned short h[8]; } u;
  u.v = *(const v8s*)(cvin + base);
  float r[8];
#pragma unroll
  for (int i = 0; i < 8; ++i)
    r[i] = fmaxf(fmaf(bf2f(u.h[i]), sc, sh), 0.f);
  *(float4*)(out + base)     = make_float4(r[0], r[1], r[2], r[3]);
  *(float4*)(out + base + 4) = make_float4(r[4], r[5], r[6], r[7]);
}

extern "C" void kernel_launch(void* const* d_in, const int* in_sizes, int n_in,
                              void* d_out, int out_size, void* d_ws, size_t ws_size,
                              hipStream_t stream) {
  const float* x      = (const float*)d_in[0];
  const float* coords = (const float*)d_in[1];
  const float* W      = (const float*)d_in[2];
  // d_in[3] = bias: cancels under training-mode BatchNorm; unused.
  const float* gamma  = (const float*)d_in[4];
  const float* beta   = (const float*)d_in[5];
  float* out = (float*)d_out;
  char* ws = (char*)d_ws;

  float* stat_sum = (float*)(ws);            // 64*64 f32
  float* stat_sq  = (float*)(ws + 16384);    // 64*64 f32
  float* ss       = (float*)(ws + 32768);    // 128 f32
  v8s*   Wt       = (v8s*)(ws + 40960);      // 73728 B
  __hip_bfloat16* scratch = (__hip_bfloat16*)(ws + 131072); // 64 MiB (optional)

  const size_t need_bf16 = (size_t)131072 + (size_t)NB * COUT * LSEQ * 2;
  const bool bf16_path = ws_size >= need_bf16;

  hipMemsetAsync(ws, 0, 32768, stream);
  wtrans_kernel<<<18, 256, 0, stream>>>(W, Wt);

  if (bf16_path) {
    conv_kernel<__hip_bfloat16><<<NB * NTILES / 4, 256, 0, stream>>>(
        x, coords, Wt, scratch, stat_sum, stat_sq);
    finalize_kernel<<<1, COUT, 0, stream>>>(stat_sum, stat_sq, gamma, beta, ss);
    scale_bf16_kernel<<<(NB * COUT * (LSEQ / 2048)), 256, 0, stream>>>(scratch, ss, out);
  } else {
    conv_kernel<float><<<NB * NTILES / 4, 256, 0, stream>>>(
        x, coords, Wt, out, stat_sum, stat_sq);
    finalize_kernel<<<1, COUT, 0, stream>>>(stat_sum, stat_sq, gamma, beta, ss);
    scale_f32_kernel<<<(NB * COUT * (LSEQ / 2048)), 256, 0, stream>>>(out, ss);
  }
}

// Round 2
// 328.468 us; speedup vs baseline: 1.0307x; 1.0307x over previous
//
#include <hip/hip_runtime.h>
#include <hip/hip_bf16.h>

#define KK 9
#define PADK 4
#define CIN 64
#define COUT 64
#define LSEQ 131072
#define NB 4
#define TILE 64
#define XROWS 72          // TILE + KK - 1
#define XRS 72            // xt row stride (bf16 elems); 144 B rows, 16B aligned
#define NTILES 2048       // LSEQ / TILE
#define NPART 64

typedef __attribute__((ext_vector_type(8))) short v8s;
typedef __attribute__((ext_vector_type(4))) float v4f;

__device__ __forceinline__ unsigned short f2bf(float f) {
  __hip_bfloat16 h = __float2bfloat16(f);
  return *reinterpret_cast<unsigned short*>(&h);
}
__device__ __forceinline__ float bf2f(unsigned short s) {
  return __uint_as_float(((unsigned)s) << 16);
}

__device__ __forceinline__ void store_o(float* p, float v) { *p = v; }
__device__ __forceinline__ void store_o(__hip_bfloat16* p, float v) { *p = __float2bfloat16(v); }

// ---------------------------------------------------------------------------
// Repack W[Cout][Cin][K] fp32 -> bf16 A-fragments for mfma_f32_16x16x32_bf16,
// pre-swizzled: frag (k, s, mblk) is 1024 contiguous bytes, lane-major.
// A-layout: lane holds A[m = lane&15][kdim = (lane>>4)*8 + j], j=0..7.
// Here m -> o within mblk, kdim -> c = 32*s + q*8 + j.
// ---------------------------------------------------------------------------
__global__ void wtrans_kernel(const float* __restrict__ W, v8s* __restrict__ Wt) {
  int t = blockIdx.x * 256 + threadIdx.x;
  if (t >= KK * 2 * 4 * 64) return;
  int lane = t & 63;
  int frag = t >> 6;
  int mblk = frag & 3;
  int s    = (frag >> 2) & 1;
  int k    = frag >> 3;
  int m = lane & 15, q = lane >> 4;
  int o = mblk * 16 + m;
  union { v8s v; unsigned short h[8]; } u;
#pragma unroll
  for (int j = 0; j < 8; ++j) {
    int c = 32 * s + q * 8 + j;
    u.h[j] = f2bf(W[(o * CIN + c) * KK + k]);
  }
  Wt[t] = u.v;
}

// ---------------------------------------------------------------------------
// Weighted conv via MFMA, telescoped per-k GEMM decomposition:
//   out[o,n] = sum_k w[k,n] * g_k[o,n],  g_k = W_k . x_shifted(k)
//            = sum_k delta[k,n] * ycum_k[o,n],  delta_k = w_k - w_{k+1}
// ycum = running MFMA accumulator (never reset); tot += delta * ycum per k.
// Inner loop is pure ds_read_b128 -> MFMA; w applied in fp32 on accumulators.
// One wave (=block) computes a 64(o) x 64(l) tile.
// ---------------------------------------------------------------------------
template <typename OutT>
__global__ __launch_bounds__(64, 3)
void conv_kernel(const float* __restrict__ x, const float* __restrict__ coords,
                 const v8s* __restrict__ Wt, OutT* __restrict__ cv,
                 float* __restrict__ stat_sum, float* __restrict__ stat_sq) {
  __shared__ __align__(16) __hip_bfloat16 xt[XROWS][XRS]; // x tile, [n'][c], bf16
  __shared__ float wt[KK][TILE];                          // delta weights

  const int lane = threadIdx.x & 63;
  const int gw   = blockIdx.x;                // wave-tile id, 0..8191
  const int b    = gw >> 11;                  // / NTILES
  const int tile = gw & (NTILES - 1);
  const int l0   = tile * TILE;
  const float* xb = x + (b * CIN) * LSEQ;
  const float* cb = coords + (b * 3) * LSEQ;
  const int m = lane & 15;
  const int q = lane >> 4;

  // ---- stage main x region (rows 4..67): 8-channel groups, b128 writes ----
#pragma unroll
  for (int rep = 0; rep < 2; ++rep) {
    int cg = 8 * (q + 4 * rep);               // channel group base
    float4 f[8];
#pragma unroll
    for (int t = 0; t < 8; ++t)
      f[t] = *(const float4*)(xb + (cg + t) * LSEQ + l0 + 4 * m);
    const float* fp = (const float*)&f[0];
#pragma unroll
    for (int j = 0; j < 4; ++j) {
      union { v8s v; unsigned short h[8]; } u;
#pragma unroll
      for (int t = 0; t < 8; ++t) u.h[t] = f2bf(fp[4 * t + j]);
      *(v8s*)&xt[4 + 4 * m + j][cg] = u.v;    // 16B aligned, conflict-free
    }
  }
  // ---- halos (rows 0..3 and 68..71), zero-padded at sequence ends ----
  {
    int c = lane;
    float el[4] = {0.f, 0.f, 0.f, 0.f};
    float er[4] = {0.f, 0.f, 0.f, 0.f};
    if (tile != 0) {
#pragma unroll
      for (int j = 0; j < 4; ++j) el[j] = xb[c * LSEQ + l0 - 4 + j];
    }
    if (tile != NTILES - 1) {
#pragma unroll
      for (int j = 0; j < 4; ++j) er[j] = xb[c * LSEQ + l0 + TILE + j];
    }
#pragma unroll
    for (int j = 0; j < 4; ++j) {
      xt[j][c]      = __float2bfloat16(el[j]);
      xt[68 + j][c] = __float2bfloat16(er[j]);
    }
  }
  // ---- gaussian weights from direct (predicated) coord loads; store delta ----
  {
    int n = lane;
    float sx = cb[l0 + n];
    float sy = cb[LSEQ + l0 + n];
    float sz = cb[2 * LSEQ + l0 + n];
    float w9[KK];
#pragma unroll
    for (int k = 0; k < KK; ++k) {
      int l = l0 + n + k - PADK;
      float cx = 0.f, cy = 0.f, cz = 0.f;
      if ((unsigned)l < (unsigned)LSEQ) {     // zero-pad like jnp.pad
        cx = cb[l]; cy = cb[LSEQ + l]; cz = cb[2 * LSEQ + l];
      }
      float dx = cx - sx, dy = cy - sy, dz = cz - sz;
      w9[k] = __expf(-0.5f * (dx * dx + dy * dy + dz * dz));
    }
#pragma unroll
    for (int k = 0; k < KK; ++k)
      wt[k][n] = w9[k] - ((k < KK - 1) ? w9[k + 1] : 0.f);
  }
  __syncthreads();

  // ---- MFMA main loop: ycum accumulates GEMMs; tot += delta * ycum per k ----
  v4f y[4][4], tot[4][4];
#pragma unroll
  for (int i = 0; i < 4; ++i)
#pragma unroll
    for (int j = 0; j < 4; ++j) {
      y[i][j]   = (v4f){0.f, 0.f, 0.f, 0.f};
      tot[i][j] = (v4f){0.f, 0.f, 0.f, 0.f};
    }

#pragma unroll 1
  for (int k = 0; k < KK; ++k) {
    const v8s* wk = Wt + k * 512;
#pragma unroll
    for (int s = 0; s < 2; ++s) {
      v8s a0 = wk[(s * 4 + 0) * 64 + lane];
      v8s a1 = wk[(s * 4 + 1) * 64 + lane];
      v8s a2 = wk[(s * 4 + 2) * 64 + lane];
      v8s a3 = wk[(s * 4 + 3) * 64 + lane];
#pragma unroll
      for (int nb = 0; nb < 4; ++nb) {
        v8s bf = *(const v8s*)&xt[nb * 16 + m + k][q * 8 + 32 * s];
        y[0][nb] = __builtin_amdgcn_mfma_f32_16x16x32_bf16(a0, bf, y[0][nb], 0, 0, 0);
        y[1][nb] = __builtin_amdgcn_mfma_f32_16x16x32_bf16(a1, bf, y[1][nb], 0, 0, 0);
        y[2][nb] = __builtin_amdgcn_mfma_f32_16x16x32_bf16(a2, bf, y[2][nb], 0, 0, 0);
        y[3][nb] = __builtin_amdgcn_mfma_f32_16x16x32_bf16(a3, bf, y[3][nb], 0, 0, 0);
      }
    }
#pragma unroll
    for (int nb = 0; nb < 4; ++nb) {
      float d = wt[k][nb * 16 + m];
#pragma unroll
      for (int mb = 0; mb < 4; ++mb)
#pragma unroll
        for (int r = 0; r < 4; ++r)
          tot[mb][nb][r] = __builtin_fmaf(d, y[mb][nb][r], tot[mb][nb][r]);
    }
  }

  // ---- epilogue: store conv result + per-channel sum/sumsq partials ----
  const int part = gw & (NPART - 1);
  OutT* outb = cv + (b * COUT) * LSEQ;
#pragma unroll
  for (int mb = 0; mb < 4; ++mb) {
#pragma unroll
    for (int r = 0; r < 4; ++r) {
      int o = mb * 16 + q * 4 + r;   // C-layout: row = q*4 + reg
      float s1 = 0.f, s2 = 0.f;
#pragma unroll
      for (int nb = 0; nb < 4; ++nb) {
        float v = tot[mb][nb][r];
        s1 += v;
        s2 += v * v;
        store_o(&outb[o * LSEQ + l0 + nb * 16 + m], v);  // col = lane&15
      }
#pragma unroll
      for (int off = 1; off < 16; off <<= 1) {
        s1 += __shfl_xor(s1, off, 64);
        s2 += __shfl_xor(s2, off, 64);
      }
      if (m == 0) {
        atomicAdd(&stat_sum[part * COUT + o], s1);
        atomicAdd(&stat_sq [part * COUT + o], s2);
      }
    }
  }
}

// ---------------------------------------------------------------------------
// BN finalize: scale = gamma*rsqrt(var+eps), shift = beta - mean*scale.
// (Conv bias cancels exactly under training-mode BN, so it is skipped.)
// ---------------------------------------------------------------------------
__global__ void finalize_kernel(const float* __restrict__ stat_sum,
                                const float* __restrict__ stat_sq,
                                const float* __restrict__ gamma,
                                const float* __restrict__ beta,
                                float* __restrict__ ss) {
  int o = threadIdx.x;
  float s1 = 0.f, s2 = 0.f;
  for (int p = 0; p < NPART; ++p) {
    s1 += stat_sum[p * COUT + o];
    s2 += stat_sq [p * COUT + o];
  }
  const float invN = 1.0f / (float)(NB * LSEQ);
  float mean = s1 * invN;
  float var  = s2 * invN - mean * mean;   // biased, matches jnp.var
  float sc = gamma[o] * rsqrtf(var + 1e-5f);
  ss[o]        = sc;
  ss[COUT + o] = beta[o] - mean * sc;
}

// ---- BN apply + ReLU; one block = 2048 contiguous elems in one channel ----
__global__ __launch_bounds__(256)
void scale_f32_kernel(float* __restrict__ data, const float* __restrict__ ss) {
  const int blk = blockIdx.x;
  const int ch = (blk >> 6) & 63;   // L/2048 = 64 blocks per channel
  const float sc = ss[ch];
  const float sh = ss[COUT + ch];
  const int base = blk * 2048 + threadIdx.x * 8;
  float4 a = *(float4*)(data + base);
  float4 b = *(float4*)(data + base + 4);
  a.x = fmaxf(fmaf(a.x, sc, sh), 0.f);
  a.y = fmaxf(fmaf(a.y, sc, sh), 0.f);
  a.z = fmaxf(fmaf(a.z, sc, sh), 0.f);
  a.w = fmaxf(fmaf(a.w, sc, sh), 0.f);
  b.x = fmaxf(fmaf(b.x, sc, sh), 0.f);
  b.y = fmaxf(fmaf(b.y, sc, sh), 0.f);
  b.z = fmaxf(fmaf(b.z, sc, sh), 0.f);
  b.w = fmaxf(fmaf(b.w, sc, sh), 0.f);
  *(float4*)(data + base)     = a;
  *(float4*)(data + base + 4) = b;
}

__global__ __launch_bounds__(256)
void scale_bf16_kernel(const __hip_bfloat16* __restrict__ cvin,
                       const float* __restrict__ ss, float* __restrict__ out) {
  const int blk = blockIdx.x;
  const int ch = (blk >> 6) & 63;
  const float sc = ss[ch];
  const float sh = ss[COUT + ch];
  const int base = blk * 2048 + threadIdx.x * 8;
  union { v8s v; unsigned short h[8]; } u;
  u.v = *(const v8s*)(cvin + base);
  float r[8];
#pragma unroll
  for (int i = 0; i < 8; ++i)
    r[i] = fmaxf(fmaf(bf2f(u.h[i]), sc, sh), 0.f);
  *(float4*)(out + base)     = make_float4(r[0], r[1], r[2], r[3]);
  *(float4*)(out + base + 4) = make_float4(r[4], r[5], r[6], r[7]);
}

extern "C" void kernel_launch(void* const* d_in, const int* in_sizes, int n_in,
                              void* d_out, int out_size, void* d_ws, size_t ws_size,
                              hipStream_t stream) {
  const float* x      = (const float*)d_in[0];
  const float* coords = (const float*)d_in[1];
  const float* W      = (const float*)d_in[2];
  // d_in[3] = bias: cancels under training-mode BatchNorm; unused.
  const float* gamma  = (const float*)d_in[4];
  const float* beta   = (const float*)d_in[5];
  float* out = (float*)d_out;
  char* ws = (char*)d_ws;

  float* stat_sum = (float*)(ws);            // 64*64 f32
  float* stat_sq  = (float*)(ws + 16384);    // 64*64 f32
  float* ss       = (float*)(ws + 32768);    // 128 f32
  v8s*   Wt       = (v8s*)(ws + 40960);      // 73728 B
  __hip_bfloat16* scratch = (__hip_bfloat16*)(ws + 131072); // 64 MiB (optional)

  const size_t need_bf16 = (size_t)131072 + (size_t)NB * COUT * LSEQ * 2;
  const bool bf16_path = ws_size >= need_bf16;

  hipMemsetAsync(ws, 0, 32768, stream);
  wtrans_kernel<<<18, 256, 0, stream>>>(W, Wt);

  if (bf16_path) {
    conv_kernel<__hip_bfloat16><<<NB * NTILES, 64, 0, stream>>>(
        x, coords, Wt, scratch, stat_sum, stat_sq);
    finalize_kernel<<<1, COUT, 0, stream>>>(stat_sum, stat_sq, gamma, beta, ss);
    scale_bf16_kernel<<<(NB * COUT * (LSEQ / 2048)), 256, 0, stream>>>(scratch, ss, out);
  } else {
    conv_kernel<float><<<NB * NTILES, 64, 0, stream>>>(
        x, coords, Wt, out, stat_sum, stat_sq);
    finalize_kernel<<<1, COUT, 0, stream>>>(stat_sum, stat_sq, gamma, beta, ss);
    scale_f32_kernel<<<(NB * COUT * (LSEQ / 2048)), 256, 0, stream>>>(out, ss);
  }
}

// Round 3
// 322.573 us; speedup vs baseline: 1.0496x; 1.0183x over previous
//
#include <hip/hip_runtime.h>
#include <hip/hip_bf16.h>

#define KK 9
#define PADK 4
#define CIN 64
#define COUT 64
#define LSEQ 131072
#define NB 4
#define TILE 64
#define XROWS 72          // TILE + KK - 1
#define XRS 72            // xt row stride (bf16 elems); 144 B rows, staggers banks
#define NTILES 2048       // LSEQ / TILE
#define NPART 64

typedef __attribute__((ext_vector_type(8))) short v8s;
typedef __attribute__((ext_vector_type(4))) float v4f;

__device__ __forceinline__ unsigned short f2bf(float f) {
  __hip_bfloat16 h = __float2bfloat16(f);
  return *reinterpret_cast<unsigned short*>(&h);
}
__device__ __forceinline__ float bf2f(unsigned short s) {
  return __uint_as_float(((unsigned)s) << 16);
}

__device__ __forceinline__ void store_o(float* p, float v) { *p = v; }
__device__ __forceinline__ void store_o(__hip_bfloat16* p, float v) { *p = __float2bfloat16(v); }

// ---------------------------------------------------------------------------
// Repack W[Cout][Cin][K] fp32 -> bf16 A-fragments for mfma_f32_16x16x32_bf16,
// pre-swizzled: frag (k, s, mblk) is 1024 contiguous bytes, lane-major.
// A-layout: lane holds A[m = lane&15][kdim = (lane>>4)*8 + j], j=0..7.
// Here m -> o within mblk, kdim -> c = 32*s + q*8 + j.
// ---------------------------------------------------------------------------
__global__ void wtrans_kernel(const float* __restrict__ W, v8s* __restrict__ Wt) {
  int t = blockIdx.x * 256 + threadIdx.x;
  if (t >= KK * 2 * 4 * 64) return;
  int lane = t & 63;
  int frag = t >> 6;
  int mblk = frag & 3;
  int s    = (frag >> 2) & 1;
  int k    = frag >> 3;
  int m = lane & 15, q = lane >> 4;
  int o = mblk * 16 + m;
  union { v8s v; unsigned short h[8]; } u;
#pragma unroll
  for (int j = 0; j < 8; ++j) {
    int c = 32 * s + q * 8 + j;
    u.h[j] = f2bf(W[(o * CIN + c) * KK + k]);
  }
  Wt[t] = u.v;
}

// ---------------------------------------------------------------------------
// Weighted conv via MFMA, telescoped per-k GEMM decomposition:
//   out[o,n] = sum_k w[k,n] * g_k[o,n]  =  sum_k delta[k,n] * ycum_k[o,n]
// One block (4 waves) computes a 64(o) x 64(l) tile; wave wv owns the 16
// o-rows of mblk wv, so per-lane accumulator state is 32 fp32 (y[4]+tot[4]).
// k-loop issue order: MFMA(k) -> reload a-frags(k+1) -> tot fmacs(k), so the
// Wt L2 latency hides behind VALU work; 5 waves/SIMD add TLP on top.
// ---------------------------------------------------------------------------
template <typename OutT>
__global__ __launch_bounds__(256, 5)
void conv_kernel(const float* __restrict__ x, const float* __restrict__ coords,
                 const v8s* __restrict__ Wt, OutT* __restrict__ cv,
                 float* __restrict__ stat_sum, float* __restrict__ stat_sq) {
  __shared__ __align__(16) __hip_bfloat16 xt[XROWS][XRS]; // x tile, [n'][c], bf16
  __shared__ float wt[KK][TILE];                          // delta weights

  const int tid  = threadIdx.x;
  const int wv   = tid >> 6;                  // 0..3 = mblk owned by this wave
  const int lane = tid & 63;
  const int gw   = blockIdx.x;                // tile id, 0..8191
  const int b    = gw >> 11;                  // / NTILES
  const int tile = gw & (NTILES - 1);
  const int l0   = tile * TILE;
  const float* xb = x + (b * CIN) * LSEQ;
  const float* cb = coords + (b * 3) * LSEQ;
  const int m = lane & 15;
  const int q = lane >> 4;

  // ---- stage main x region (rows 4..67): each thread 4 channels x 4 l ----
  {
    int mm = tid & 15;                        // l-chunk
    int c4 = (tid >> 4) * 4;                  // channel group of 4
    float4 f[4];
#pragma unroll
    for (int t = 0; t < 4; ++t)
      f[t] = *(const float4*)(xb + (c4 + t) * LSEQ + l0 + 4 * mm);
    const float* fp = (const float*)&f[0];
#pragma unroll
    for (int j = 0; j < 4; ++j) {
      union { unsigned long long v; unsigned short h[4]; } u;
#pragma unroll
      for (int t = 0; t < 4; ++t) u.h[t] = f2bf(fp[4 * t + j]);
      *(unsigned long long*)&xt[4 + 4 * mm + j][c4] = u.v;
    }
  }
  // ---- halos (rows 0..3 and 68..71), zero-padded at sequence ends ----
  if (tid < 128) {
    int side = tid >> 6;
    int c = tid & 63;
    if (side == 0) {
      float el[4] = {0.f, 0.f, 0.f, 0.f};
      if (tile != 0) {
#pragma unroll
        for (int j = 0; j < 4; ++j) el[j] = xb[c * LSEQ + l0 - 4 + j];
      }
#pragma unroll
      for (int j = 0; j < 4; ++j) xt[j][c] = __float2bfloat16(el[j]);
    } else {
      float er[4] = {0.f, 0.f, 0.f, 0.f};
      if (tile != NTILES - 1) {
#pragma unroll
        for (int j = 0; j < 4; ++j) er[j] = xb[c * LSEQ + l0 + TILE + j];
      }
#pragma unroll
      for (int j = 0; j < 4; ++j) xt[68 + j][c] = __float2bfloat16(er[j]);
    }
  }
  // ---- gaussian delta weights from predicated coord loads ----
  if (tid < 64) {
    int n = tid;
    float sx = cb[l0 + n];
    float sy = cb[LSEQ + l0 + n];
    float sz = cb[2 * LSEQ + l0 + n];
    float w9[KK];
#pragma unroll
    for (int k = 0; k < KK; ++k) {
      int l = l0 + n + k - PADK;
      float cx = 0.f, cy = 0.f, cz = 0.f;
      if ((unsigned)l < (unsigned)LSEQ) {     // zero-pad like jnp.pad
        cx = cb[l]; cy = cb[LSEQ + l]; cz = cb[2 * LSEQ + l];
      }
      float dx = cx - sx, dy = cy - sy, dz = cz - sz;
      w9[k] = __expf(-0.5f * (dx * dx + dy * dy + dz * dz));
    }
#pragma unroll
    for (int k = 0; k < KK; ++k)
      wt[k][n] = w9[k] - ((k < KK - 1) ? w9[k + 1] : 0.f);
  }
  __syncthreads();

  // ---- MFMA main loop ----
  v4f y[4], tot[4];
#pragma unroll
  for (int j = 0; j < 4; ++j) {
    y[j]   = (v4f){0.f, 0.f, 0.f, 0.f};
    tot[j] = (v4f){0.f, 0.f, 0.f, 0.f};
  }

  // frag(k,s,mb) at Wt[k*512 + s*256 + mb*64 + lane]
  const v8s* wp = Wt + wv * 64 + lane;
  v8s a0 = wp[0];
  v8s a1 = wp[256];

#pragma unroll 1
  for (int k = 0; k < KK; ++k) {
    // MFMAs for k (consume a0/a1)
#pragma unroll
    for (int nbq = 0; nbq < 4; ++nbq) {
      const __hip_bfloat16* rowp = &xt[nbq * 16 + m + k][q * 8];
      v8s b0 = *(const v8s*)(rowp);
      v8s b1 = *(const v8s*)(rowp + 32);
      y[nbq] = __builtin_amdgcn_mfma_f32_16x16x32_bf16(a0, b0, y[nbq], 0, 0, 0);
      y[nbq] = __builtin_amdgcn_mfma_f32_16x16x32_bf16(a1, b1, y[nbq], 0, 0, 0);
    }
    // single-buffer reload for k+1 (a regs are dead once MFMAs issued)
    int kn = k + (k < KK - 1);
    a0 = wp[kn * 512];
    a1 = wp[kn * 512 + 256];
    // telescoping accumulate (hides the reload latency)
#pragma unroll
    for (int nbq = 0; nbq < 4; ++nbq) {
      float d = wt[k][nbq * 16 + m];
#pragma unroll
      for (int r = 0; r < 4; ++r)
        tot[nbq][r] = __builtin_fmaf(d, y[nbq][r], tot[nbq][r]);
    }
  }

  // ---- epilogue: store conv result + per-channel sum/sumsq partials ----
  const int part = gw & (NPART - 1);
  OutT* outb = cv + (b * COUT) * LSEQ;
#pragma unroll
  for (int r = 0; r < 4; ++r) {
    int o = wv * 16 + q * 4 + r;   // C-layout: row = q*4 + reg
    float s1 = 0.f, s2 = 0.f;
#pragma unroll
    for (int nbq = 0; nbq < 4; ++nbq) {
      float v = tot[nbq][r];
      s1 += v;
      s2 += v * v;
      store_o(&outb[o * LSEQ + l0 + nbq * 16 + m], v);  // col = lane&15
    }
#pragma unroll
    for (int off = 1; off < 16; off <<= 1) {
      s1 += __shfl_xor(s1, off, 64);
      s2 += __shfl_xor(s2, off, 64);
    }
    if (m == 0) {
      atomicAdd(&stat_sum[part * COUT + o], s1);
      atomicAdd(&stat_sq [part * COUT + o], s2);
    }
  }
}

// ---------------------------------------------------------------------------
// BN finalize: scale = gamma*rsqrt(var+eps), shift = beta - mean*scale.
// (Conv bias cancels exactly under training-mode BN, so it is skipped.)
// ---------------------------------------------------------------------------
__global__ void finalize_kernel(const float* __restrict__ stat_sum,
                                const float* __restrict__ stat_sq,
                                const float* __restrict__ gamma,
                                const float* __restrict__ beta,
                                float* __restrict__ ss) {
  int o = threadIdx.x;
  float s1 = 0.f, s2 = 0.f;
  for (int p = 0; p < NPART; ++p) {
    s1 += stat_sum[p * COUT + o];
    s2 += stat_sq [p * COUT + o];
  }
  const float invN = 1.0f / (float)(NB * LSEQ);
  float mean = s1 * invN;
  float var  = s2 * invN - mean * mean;   // biased, matches jnp.var
  float sc = gamma[o] * rsqrtf(var + 1e-5f);
  ss[o]        = sc;
  ss[COUT + o] = beta[o] - mean * sc;
}

// ---- BN apply + ReLU; one block = 2048 contiguous elems in one channel ----
__global__ __launch_bounds__(256)
void scale_f32_kernel(float* __restrict__ data, const float* __restrict__ ss) {
  const int blk = blockIdx.x;
  const int ch = (blk >> 6) & 63;   // L/2048 = 64 blocks per channel
  const float sc = ss[ch];
  const float sh = ss[COUT + ch];
  const int base = blk * 2048 + threadIdx.x * 8;
  float4 a = *(float4*)(data + base);
  float4 b = *(float4*)(data + base + 4);
  a.x = fmaxf(fmaf(a.x, sc, sh), 0.f);
  a.y = fmaxf(fmaf(a.y, sc, sh), 0.f);
  a.z = fmaxf(fmaf(a.z, sc, sh), 0.f);
  a.w = fmaxf(fmaf(a.w, sc, sh), 0.f);
  b.x = fmaxf(fmaf(b.x, sc, sh), 0.f);
  b.y = fmaxf(fmaf(b.y, sc, sh), 0.f);
  b.z = fmaxf(fmaf(b.z, sc, sh), 0.f);
  b.w = fmaxf(fmaf(b.w, sc, sh), 0.f);
  *(float4*)(data + base)     = a;
  *(float4*)(data + base + 4) = b;
}

__global__ __launch_bounds__(256)
void scale_bf16_kernel(const __hip_bfloat16* __restrict__ cvin,
                       const float* __restrict__ ss, float* __restrict__ out) {
  const int blk = blockIdx.x;
  const int ch = (blk >> 6) & 63;
  const float sc = ss[ch];
  const float sh = ss[COUT + ch];
  const int base = blk * 2048 + threadIdx.x * 8;
  union { v8s v; unsigned short h[8]; } u;
  u.v = *(const v8s*)(cvin + base);
  float r[8];
#pragma unroll
  for (int i = 0; i < 8; ++i)
    r[i] = fmaxf(fmaf(bf2f(u.h[i]), sc, sh), 0.f);
  *(float4*)(out + base)     = make_float4(r[0], r[1], r[2], r[3]);
  *(float4*)(out + base + 4) = make_float4(r[4], r[5], r[6], r[7]);
}

extern "C" void kernel_launch(void* const* d_in, const int* in_sizes, int n_in,
                              void* d_out, int out_size, void* d_ws, size_t ws_size,
                              hipStream_t stream) {
  const float* x      = (const float*)d_in[0];
  const float* coords = (const float*)d_in[1];
  const float* W      = (const float*)d_in[2];
  // d_in[3] = bias: cancels under training-mode BatchNorm; unused.
  const float* gamma  = (const float*)d_in[4];
  const float* beta   = (const float*)d_in[5];
  float* out = (float*)d_out;
  char* ws = (char*)d_ws;

  float* stat_sum = (float*)(ws);            // 64*64 f32
  float* stat_sq  = (float*)(ws + 16384);    // 64*64 f32
  float* ss       = (float*)(ws + 32768);    // 128 f32
  v8s*   Wt       = (v8s*)(ws + 40960);      // 73728 B
  __hip_bfloat16* scratch = (__hip_bfloat16*)(ws + 131072); // 64 MiB (optional)

  const size_t need_bf16 = (size_t)131072 + (size_t)NB * COUT * LSEQ * 2;
  const bool bf16_path = ws_size >= need_bf16;

  hipMemsetAsync(ws, 0, 32768, stream);
  wtrans_kernel<<<18, 256, 0, stream>>>(W, Wt);

  if (bf16_path) {
    conv_kernel<__hip_bfloat16><<<NB * NTILES, 256, 0, stream>>>(
        x, coords, Wt, scratch, stat_sum, stat_sq);
    finalize_kernel<<<1, COUT, 0, stream>>>(stat_sum, stat_sq, gamma, beta, ss);
    scale_bf16_kernel<<<(NB * COUT * (LSEQ / 2048)), 256, 0, stream>>>(scratch, ss, out);
  } else {
    conv_kernel<float><<<NB * NTILES, 256, 0, stream>>>(
        x, coords, Wt, out, stat_sum, stat_sq);
    finalize_kernel<<<1, COUT, 0, stream>>>(stat_sum, stat_sq, gamma, beta, ss);
    scale_f32_kernel<<<(NB * COUT * (LSEQ / 2048)), 256, 0, stream>>>(out, ss);
  }
}

// Round 4
// 320.997 us; speedup vs baseline: 1.0547x; 1.0049x over previous
//
#include <hip/hip_runtime.h>
#include <hip/hip_bf16.h>

#define KK 9
#define PADK 4
#define CIN 64
#define COUT 64
#define LSEQ 131072
#define NB 4
#define TILEL 128         // l-extent of a block tile
#define XROWS 136         // TILEL + KK - 1
#define XRS 72            // xt row stride (bf16); 144 B rows -> uniform 8/bank reads
#define NTILES 1024       // LSEQ / TILEL
#define NPART 64

typedef __attribute__((ext_vector_type(8))) short v8s;
typedef __attribute__((ext_vector_type(4))) float v4f;

__device__ __forceinline__ unsigned short f2bf(float f) {
  __hip_bfloat16 h = __float2bfloat16(f);
  return *reinterpret_cast<unsigned short*>(&h);
}
__device__ __forceinline__ float bf2f(unsigned short s) {
  return __uint_as_float(((unsigned)s) << 16);
}

__device__ __forceinline__ void store_o(float* p, float v) { *p = v; }
__device__ __forceinline__ void store_o(__hip_bfloat16* p, float v) { *p = __float2bfloat16(v); }

// ---------------------------------------------------------------------------
// Repack W[Cout][Cin][K] fp32 -> bf16 A-fragments for mfma_f32_16x16x32_bf16,
// pre-swizzled: frag (k, s, mblk) is 1024 contiguous bytes, lane-major.
// A-layout: lane holds A[m = lane&15][kdim = (lane>>4)*8 + j], j=0..7.
// Here m -> o within mblk, kdim -> c = 32*s + q*8 + j.
// ---------------------------------------------------------------------------
__global__ void wtrans_kernel(const float* __restrict__ W, v8s* __restrict__ Wt) {
  int t = blockIdx.x * 256 + threadIdx.x;
  if (t >= KK * 2 * 4 * 64) return;
  int lane = t & 63;
  int frag = t >> 6;
  int mblk = frag & 3;
  int s    = (frag >> 2) & 1;
  int k    = frag >> 3;
  int m = lane & 15, q = lane >> 4;
  int o = mblk * 16 + m;
  union { v8s v; unsigned short h[8]; } u;
#pragma unroll
  for (int j = 0; j < 8; ++j) {
    int c = 32 * s + q * 8 + j;
    u.h[j] = f2bf(W[(o * CIN + c) * KK + k]);
  }
  Wt[t] = u.v;
}

// ---------------------------------------------------------------------------
// Weighted conv via MFMA, telescoped per-k GEMM decomposition:
//   out[o,n] = sum_k w[k,n] * g_k[o,n]  =  sum_k delta[k,n] * ycum_k[o,n]
// Block (4 waves) computes a 64(o) x 128(l) tile; wave (wo,wl) owns
// 32 o-rows x 64 l-cols, so B-frags are read by 2 waves (2x redundancy, was
// 4x in R3) and A-frags by 2 waves through L1. Per-lane acc = 64 fp32.
// ---------------------------------------------------------------------------
template <typename OutT>
__global__ __launch_bounds__(256, 4)
void conv_kernel(const float* __restrict__ x, const float* __restrict__ coords,
                 const v8s* __restrict__ Wt, OutT* __restrict__ cv,
                 float* __restrict__ stat_sum, float* __restrict__ stat_sq) {
  __shared__ __align__(16) __hip_bfloat16 xt[XROWS][XRS]; // x tile, [n'][c], bf16
  __shared__ float wt[KK][TILEL];                         // delta weights

  const int tid  = threadIdx.x;
  const int wv   = tid >> 6;
  const int wo   = wv & 1;                    // o-half (32 rows)
  const int wl   = wv >> 1;                   // l-half (64 cols)
  const int lane = tid & 63;
  const int gw   = blockIdx.x;                // tile id, 0..4095
  const int b    = gw >> 10;                  // / NTILES
  const int tile = gw & (NTILES - 1);
  const int l0   = tile * TILEL;
  const float* xb = x + (b * CIN) * LSEQ;
  const float* cb = coords + (b * 3) * LSEQ;
  const int m = lane & 15;
  const int q = lane >> 4;

  // ---- stage main x region (rows 4..131): lane-inner = channel-group so each
  //      b128 LDS write covers all 32 banks uniformly (8/bank = floor) ----
  {
    int cg = tid & 7;                         // channel group (8 ch each)
    int lc = tid >> 3;                        // l-chunk 0..31 (4 l each)
    int c8 = cg * 8;
    float4 f[8];
#pragma unroll
    for (int t = 0; t < 8; ++t)
      f[t] = *(const float4*)(xb + (c8 + t) * LSEQ + l0 + 4 * lc);
    const float* fp = (const float*)&f[0];
#pragma unroll
    for (int j = 0; j < 4; ++j) {
      union { v8s v; unsigned short h[8]; } u;
#pragma unroll
      for (int t = 0; t < 8; ++t) u.h[t] = f2bf(fp[4 * t + j]);
      *(v8s*)&xt[4 + 4 * lc + j][c8] = u.v;
    }
  }
  // ---- halos (rows 0..3 and 132..135), zero-padded at sequence ends ----
  if (tid < 128) {
    int side = tid >> 6;
    int c = tid & 63;
    if (side == 0) {
      float el[4] = {0.f, 0.f, 0.f, 0.f};
      if (tile != 0) {
#pragma unroll
        for (int j = 0; j < 4; ++j) el[j] = xb[c * LSEQ + l0 - 4 + j];
      }
#pragma unroll
      for (int j = 0; j < 4; ++j) xt[j][c] = __float2bfloat16(el[j]);
    } else {
      float er[4] = {0.f, 0.f, 0.f, 0.f};
      if (tile != NTILES - 1) {
#pragma unroll
        for (int j = 0; j < 4; ++j) er[j] = xb[c * LSEQ + l0 + TILEL + j];
      }
#pragma unroll
      for (int j = 0; j < 4; ++j) xt[128 + 4 + j][c] = __float2bfloat16(er[j]);
    }
  }
  // ---- gaussian delta weights from predicated coord loads ----
  if (tid < TILEL) {
    int n = tid;
    float sx = cb[l0 + n];
    float sy = cb[LSEQ + l0 + n];
    float sz = cb[2 * LSEQ + l0 + n];
    float w9[KK];
#pragma unroll
    for (int k = 0; k < KK; ++k) {
      int l = l0 + n + k - PADK;
      float cx = 0.f, cy = 0.f, cz = 0.f;
      if ((unsigned)l < (unsigned)LSEQ) {     // zero-pad like jnp.pad
        cx = cb[l]; cy = cb[LSEQ + l]; cz = cb[2 * LSEQ + l];
      }
      float dx = cx - sx, dy = cy - sy, dz = cz - sz;
      w9[k] = __expf(-0.5f * (dx * dx + dy * dy + dz * dz));
    }
#pragma unroll
    for (int k = 0; k < KK; ++k)
      wt[k][n] = w9[k] - ((k < KK - 1) ? w9[k + 1] : 0.f);
  }
  __syncthreads();

  // ---- MFMA main loop ----
  v4f y[2][4], tot[2][4];
#pragma unroll
  for (int i = 0; i < 2; ++i)
#pragma unroll
    for (int j = 0; j < 4; ++j) {
      y[i][j]   = (v4f){0.f, 0.f, 0.f, 0.f};
      tot[i][j] = (v4f){0.f, 0.f, 0.f, 0.f};
    }

  // frag(k,s,mb) at Wt[k*512 + s*256 + mb*64 + lane]
  const v8s* wp = Wt + (wo * 2) * 64 + lane;

#pragma unroll 1
  for (int k = 0; k < KK; ++k) {
#pragma unroll
    for (int s = 0; s < 2; ++s) {
      v8s a0 = wp[k * 512 + s * 256];
      v8s a1 = wp[k * 512 + s * 256 + 64];
#pragma unroll
      for (int nbq = 0; nbq < 4; ++nbq) {
        v8s bf = *(const v8s*)&xt[wl * 64 + nbq * 16 + m + k][q * 8 + 32 * s];
        y[0][nbq] = __builtin_amdgcn_mfma_f32_16x16x32_bf16(a0, bf, y[0][nbq], 0, 0, 0);
        y[1][nbq] = __builtin_amdgcn_mfma_f32_16x16x32_bf16(a1, bf, y[1][nbq], 0, 0, 0);
      }
    }
    // telescoping accumulate
#pragma unroll
    for (int nbq = 0; nbq < 4; ++nbq) {
      float d = wt[k][wl * 64 + nbq * 16 + m];
#pragma unroll
      for (int mb = 0; mb < 2; ++mb)
#pragma unroll
        for (int r = 0; r < 4; ++r)
          tot[mb][nbq][r] = __builtin_fmaf(d, y[mb][nbq][r], tot[mb][nbq][r]);
    }
  }

  // ---- epilogue: store conv result + per-channel sum/sumsq partials ----
  const int part = gw & (NPART - 1);
  OutT* outb = cv + (b * COUT) * LSEQ;
#pragma unroll
  for (int mb = 0; mb < 2; ++mb) {
#pragma unroll
    for (int r = 0; r < 4; ++r) {
      int o = wo * 32 + mb * 16 + q * 4 + r;   // C-layout: row = q*4 + reg
      float s1 = 0.f, s2 = 0.f;
#pragma unroll
      for (int nbq = 0; nbq < 4; ++nbq) {
        float v = tot[mb][nbq][r];
        s1 += v;
        s2 += v * v;
        store_o(&outb[o * LSEQ + l0 + wl * 64 + nbq * 16 + m], v); // col = lane&15
      }
#pragma unroll
      for (int off = 1; off < 16; off <<= 1) {
        s1 += __shfl_xor(s1, off, 64);
        s2 += __shfl_xor(s2, off, 64);
      }
      if (m == 0) {
        atomicAdd(&stat_sum[part * COUT + o], s1);
        atomicAdd(&stat_sq [part * COUT + o], s2);
      }
    }
  }
}

// ---------------------------------------------------------------------------
// BN finalize: scale = gamma*rsqrt(var+eps), shift = beta - mean*scale.
// (Conv bias cancels exactly under training-mode BN, so it is skipped.)
// ---------------------------------------------------------------------------
__global__ void finalize_kernel(const float* __restrict__ stat_sum,
                                const float* __restrict__ stat_sq,
                                const float* __restrict__ gamma,
                                const float* __restrict__ beta,
                                float* __restrict__ ss) {
  int o = threadIdx.x;
  float s1 = 0.f, s2 = 0.f;
  for (int p = 0; p < NPART; ++p) {
    s1 += stat_sum[p * COUT + o];
    s2 += stat_sq [p * COUT + o];
  }
  const float invN = 1.0f / (float)(NB * LSEQ);
  float mean = s1 * invN;
  float var  = s2 * invN - mean * mean;   // biased, matches jnp.var
  float sc = gamma[o] * rsqrtf(var + 1e-5f);
  ss[o]        = sc;
  ss[COUT + o] = beta[o] - mean * sc;
}

// ---- BN apply + ReLU; one block = 2048 contiguous elems in one channel ----
__global__ __launch_bounds__(256)
void scale_f32_kernel(float* __restrict__ data, const float* __restrict__ ss) {
  const int blk = blockIdx.x;
  const int ch = (blk >> 6) & 63;   // L/2048 = 64 blocks per channel
  const float sc = ss[ch];
  const float sh = ss[COUT + ch];
  const int base = blk * 2048 + threadIdx.x * 8;
  float4 a = *(float4*)(data + base);
  float4 b = *(float4*)(data + base + 4);
  a.x = fmaxf(fmaf(a.x, sc, sh), 0.f);
  a.y = fmaxf(fmaf(a.y, sc, sh), 0.f);
  a.z = fmaxf(fmaf(a.z, sc, sh), 0.f);
  a.w = fmaxf(fmaf(a.w, sc, sh), 0.f);
  b.x = fmaxf(fmaf(b.x, sc, sh), 0.f);
  b.y = fmaxf(fmaf(b.y, sc, sh), 0.f);
  b.z = fmaxf(fmaf(b.z, sc, sh), 0.f);
  b.w = fmaxf(fmaf(b.w, sc, sh), 0.f);
  *(float4*)(data + base)     = a;
  *(float4*)(data + base + 4) = b;
}

__global__ __launch_bounds__(256)
void scale_bf16_kernel(const __hip_bfloat16* __restrict__ cvin,
                       const float* __restrict__ ss, float* __restrict__ out) {
  const int blk = blockIdx.x;
  const int ch = (blk >> 6) & 63;
  const float sc = ss[ch];
  const float sh = ss[COUT + ch];
  const int base = blk * 2048 + threadIdx.x * 8;
  union { v8s v; unsigned short h[8]; } u;
  u.v = *(const v8s*)(cvin + base);
  float r[8];
#pragma unroll
  for (int i = 0; i < 8; ++i)
    r[i] = fmaxf(fmaf(bf2f(u.h[i]), sc, sh), 0.f);
  *(float4*)(out + base)     = make_float4(r[0], r[1], r[2], r[3]);
  *(float4*)(out + base + 4) = make_float4(r[4], r[5], r[6], r[7]);
}

extern "C" void kernel_launch(void* const* d_in, const int* in_sizes, int n_in,
                              void* d_out, int out_size, void* d_ws, size_t ws_size,
                              hipStream_t stream) {
  const float* x      = (const float*)d_in[0];
  const float* coords = (const float*)d_in[1];
  const float* W      = (const float*)d_in[2];
  // d_in[3] = bias: cancels under training-mode BatchNorm; unused.
  const float* gamma  = (const float*)d_in[4];
  const float* beta   = (const float*)d_in[5];
  float* out = (float*)d_out;
  char* ws = (char*)d_ws;

  float* stat_sum = (float*)(ws);            // 64*64 f32
  float* stat_sq  = (float*)(ws + 16384);    // 64*64 f32
  float* ss       = (float*)(ws + 32768);    // 128 f32
  v8s*   Wt       = (v8s*)(ws + 40960);      // 73728 B
  __hip_bfloat16* scratch = (__hip_bfloat16*)(ws + 131072); // 64 MiB (optional)

  const size_t need_bf16 = (size_t)131072 + (size_t)NB * COUT * LSEQ * 2;
  const bool bf16_path = ws_size >= need_bf16;

  hipMemsetAsync(ws, 0, 32768, stream);
  wtrans_kernel<<<18, 256, 0, stream>>>(W, Wt);

  if (bf16_path) {
    conv_kernel<__hip_bfloat16><<<NB * NTILES, 256, 0, stream>>>(
        x, coords, Wt, scratch, stat_sum, stat_sq);
    finalize_kernel<<<1, COUT, 0, stream>>>(stat_sum, stat_sq, gamma, beta, ss);
    scale_bf16_kernel<<<(NB * COUT * (LSEQ / 2048)), 256, 0, stream>>>(scratch, ss, out);
  } else {
    conv_kernel<float><<<NB * NTILES, 256, 0, stream>>>(
        x, coords, Wt, out, stat_sum, stat_sq);
    finalize_kernel<<<1, COUT, 0, stream>>>(stat_sum, stat_sq, gamma, beta, ss);
    scale_f32_kernel<<<(NB * COUT * (LSEQ / 2048)), 256, 0, stream>>>(out, ss);
  }
}